// Round 2
// baseline (269.381 us; speedup 1.0000x reference)
//
#include <hip/hip_runtime.h>
#include <hip/hip_bf16.h>

#define NN 1024
#define BB 8
#define HH 8
#define FF 64
#define HF 512
#define D_LAB 256
#define D_VIS 512

// ---------------- Kernel 1: Wh_lab = labels @ W[0:256], plus per-node e_src/e_dst parts
__global__ void k_wh_lab(const float* __restrict__ lab,   // (N, 256)
                         const float* __restrict__ Wm,    // (768, 512)
                         const float* __restrict__ a_src, // (8, 64)
                         const float* __restrict__ a_dst, // (8, 64)
                         float* __restrict__ wh,          // (N, 512)
                         float* __restrict__ es,          // (N, 8)
                         float* __restrict__ ed)          // (N, 8)
{
    int n = blockIdx.x, t = threadIdx.x;
    __shared__ float xs[D_LAB];
    __shared__ float whs[HF];
    xs[t] = lab[n * D_LAB + t];
    __syncthreads();
    float a0 = 0.f, a1 = 0.f;
    #pragma unroll 4
    for (int i = 0; i < D_LAB; ++i) {
        float xv = xs[i];
        a0 += xv * Wm[i * HF + t];
        a1 += xv * Wm[i * HF + t + 256];
    }
    wh[n * HF + t] = a0;
    wh[n * HF + t + 256] = a1;
    whs[t] = a0; whs[t + 256] = a1;
    __syncthreads();
    if (t < HH) {
        float s = 0.f, d = 0.f;
        for (int f = 0; f < FF; ++f) {
            float w = whs[t * FF + f];
            s += w * a_src[t * FF + f];
            d += w * a_dst[t * FF + f];
        }
        es[n * HH + t] = s;
        ed[n * HH + t] = d;
    }
}

// ---------------- Kernel 2: Wh_vis = visual @ W[256:768], plus per-batch e parts
__global__ void k_wh_vis(const float* __restrict__ vis,   // (B, 512)
                         const float* __restrict__ Wm,    // (768, 512)
                         const float* __restrict__ a_src,
                         const float* __restrict__ a_dst,
                         float* __restrict__ whv,         // (B, 512)
                         float* __restrict__ esv,         // (B, 8)
                         float* __restrict__ edv)         // (B, 8)
{
    int b = blockIdx.x, t = threadIdx.x;
    __shared__ float xs[D_VIS];
    __shared__ float whs[HF];
    for (int i = t; i < D_VIS; i += 256) xs[i] = vis[b * D_VIS + i];
    __syncthreads();
    float a0 = 0.f, a1 = 0.f;
    #pragma unroll 4
    for (int i = 0; i < D_VIS; ++i) {
        float xv = xs[i];
        a0 += xv * Wm[(D_LAB + i) * HF + t];
        a1 += xv * Wm[(D_LAB + i) * HF + t + 256];
    }
    whv[b * HF + t] = a0;
    whv[b * HF + t + 256] = a1;
    whs[t] = a0; whs[t + 256] = a1;
    __syncthreads();
    if (t < HH) {
        float s = 0.f, d = 0.f;
        for (int f = 0; f < FF; ++f) {
            float w = whs[t * FF + f];
            s += w * a_src[t * FF + f];
            d += w * a_dst[t * FF + f];
        }
        esv[b * HH + t] = s;
        edv[b * HH + t] = d;
    }
}

// ---------------- Kernel 3: compact adjacency rows to neighbor lists (order-free)
__global__ void k_compact(const float* __restrict__ adj,  // (N, N)
                          int* __restrict__ list,         // (N, N) capacity
                          int* __restrict__ cnt)          // (N)
{
    int i = blockIdx.x, t = threadIdx.x;
    __shared__ int c;
    if (t == 0) c = 0;
    __syncthreads();
    for (int j = t; j < NN; j += 256) {
        if (adj[i * NN + j] > 0.f) {
            int p = atomicAdd(&c, 1);
            list[i * NN + p] = j;
        }
    }
    __syncthreads();
    if (t == 0) cnt[i] = c;
}

// ---------------- Kernel 4: per-(b,i) sparse masked softmax + aggregation + ELU + score partial
__global__ void __launch_bounds__(256)
k_attn(const float* __restrict__ wh_lab,   // (N, 512)
       const float* __restrict__ wh_vis,   // (B, 512)
       const float* __restrict__ es_lab,   // (N, 8)
       const float* __restrict__ ed_lab,   // (N, 8)
       const float* __restrict__ es_vis,   // (B, 8)
       const float* __restrict__ ed_vis,   // (B, 8)
       const int* __restrict__ list, const int* __restrict__ cnt,
       const float* __restrict__ pool_q,   // (512)
       float* __restrict__ xout,           // (B, N, 512)
       float* __restrict__ scores)         // (B, N)
{
    int i = blockIdx.x, b = blockIdx.y, t = threadIdx.x;
    int lane = t & 63, wid = t >> 6;
    int nn = cnt[i];

    __shared__ float att[NN * HH];   // 32 KB
    __shared__ int jl[NN];           // 4 KB
    __shared__ float redm[4][HH], mxs[HH], invs[HH];
    __shared__ float redsum[4];

    // per-(b,i,h) base = e_src[b,i,h] + e_dst_vis[b,h]
    float base[HH];
    #pragma unroll
    for (int h = 0; h < HH; ++h)
        base[h] = es_lab[i * HH + h] + es_vis[b * HH + h] + ed_vis[b * HH + h];

    // Phase A: e = leaky(base + ed_lab[j]), track max
    float mx[HH];
    #pragma unroll
    for (int h = 0; h < HH; ++h) mx[h] = -1e30f;
    for (int k = t; k < nn; k += 256) {
        int j = list[i * NN + k];
        jl[k] = j;
        #pragma unroll
        for (int h = 0; h < HH; ++h) {
            float e = base[h] + ed_lab[j * HH + h];
            e = e > 0.f ? e : 0.2f * e;
            att[k * HH + h] = e;
            mx[h] = fmaxf(mx[h], e);
        }
    }
    #pragma unroll
    for (int h = 0; h < HH; ++h) {
        float v = mx[h];
        for (int off = 32; off > 0; off >>= 1) v = fmaxf(v, __shfl_down(v, off));
        if (lane == 0) redm[wid][h] = v;
    }
    __syncthreads();
    if (t < HH)
        mxs[t] = fmaxf(fmaxf(redm[0][t], redm[1][t]), fmaxf(redm[2][t], redm[3][t]));
    __syncthreads();

    // Phase B: exp, sum
    float sm[HH];
    #pragma unroll
    for (int h = 0; h < HH; ++h) sm[h] = 0.f;
    for (int k = t; k < nn; k += 256) {
        #pragma unroll
        for (int h = 0; h < HH; ++h) {
            float p = __expf(att[k * HH + h] - mxs[h]);
            att[k * HH + h] = p;
            sm[h] += p;
        }
    }
    #pragma unroll
    for (int h = 0; h < HH; ++h) {
        float v = sm[h];
        for (int off = 32; off > 0; off >>= 1) v += __shfl_down(v, off);
        if (lane == 0) redm[wid][h] = v;
    }
    __syncthreads();
    if (t < HH) invs[t] = 1.0f / (redm[0][t] + redm[1][t] + redm[2][t] + redm[3][t]);
    __syncthreads();

    // Phase C: aggregate out[hf] = sum_k att[k,h] * wh_lab[j, hf]
    int h0 = t >> 6;        // head for hf = t        (0..3)
    int h1 = h0 + 4;        // head for hf = t + 256  (4..7)
    float acc0 = 0.f, acc1 = 0.f;
    for (int k = 0; k < nn; ++k) {
        int j = jl[k];
        const float* row = wh_lab + j * HF;
        acc0 += att[k * HH + h0] * row[t];
        acc1 += att[k * HH + h1] * row[t + 256];
    }
    float o0 = acc0 * invs[h0] + wh_vis[b * HF + t];
    float o1 = acc1 * invs[h1] + wh_vis[b * HF + t + 256];
    // ELU
    o0 = o0 > 0.f ? o0 : (__expf(o0) - 1.f);
    o1 = o1 > 0.f ? o1 : (__expf(o1) - 1.f);
    xout[(size_t)(b * NN + i) * HF + t] = o0;
    xout[(size_t)(b * NN + i) * HF + t + 256] = o1;

    // pooling score partial: x . pool_q
    float sp = o0 * pool_q[t] + o1 * pool_q[t + 256];
    for (int off = 32; off > 0; off >>= 1) sp += __shfl_down(sp, off);
    if (lane == 0) redsum[wid] = sp;
    __syncthreads();
    if (t == 0)
        scores[b * NN + i] = redsum[0] + redsum[1] + redsum[2] + redsum[3];
}

// ---------------- Kernel 5: node softmax pooling + FC
__global__ void k_pool_fc(const float* __restrict__ xout,    // (B, N, 512)
                          const float* __restrict__ scores,  // (B, N)
                          const float* __restrict__ fc_W,    // (512, 512)
                          const float* __restrict__ fc_b,    // (512)
                          float* __restrict__ out)           // (B, 512)
{
    int b = blockIdx.x, t = threadIdx.x;
    int lane = t & 63, wid = t >> 6;
    __shared__ float ws[NN];
    __shared__ float red[4];
    __shared__ float sMx, sInv;
    __shared__ float pooled[HF];

    float mx = -1e30f;
    for (int n = t; n < NN; n += 256) {
        float s = scores[b * NN + n];
        ws[n] = s;
        mx = fmaxf(mx, s);
    }
    for (int off = 32; off > 0; off >>= 1) mx = fmaxf(mx, __shfl_down(mx, off));
    if (lane == 0) red[wid] = mx;
    __syncthreads();
    if (t == 0) sMx = fmaxf(fmaxf(red[0], red[1]), fmaxf(red[2], red[3]));
    __syncthreads();
    float sm = 0.f;
    for (int n = t; n < NN; n += 256) {
        float p = __expf(ws[n] - sMx);
        ws[n] = p;
        sm += p;
    }
    for (int off = 32; off > 0; off >>= 1) sm += __shfl_down(sm, off);
    if (lane == 0) red[wid] = sm;
    __syncthreads();
    if (t == 0) sInv = 1.0f / (red[0] + red[1] + red[2] + red[3]);
    __syncthreads();

    float p0 = 0.f, p1 = 0.f;
    for (int n = 0; n < NN; ++n) {
        float w = ws[n];
        const float* row = xout + (size_t)(b * NN + n) * HF;
        p0 += w * row[t];
        p1 += w * row[t + 256];
    }
    pooled[t] = p0 * sInv;
    pooled[t + 256] = p1 * sInv;
    __syncthreads();

    float a0 = fc_b[t], a1 = fc_b[t + 256];
    #pragma unroll 4
    for (int d = 0; d < HF; ++d) {
        float pv = pooled[d];
        a0 += pv * fc_W[d * HF + t];
        a1 += pv * fc_W[d * HF + t + 256];
    }
    out[b * HF + t] = a0;
    out[b * HF + t + 256] = a1;
}

extern "C" void kernel_launch(void* const* d_in, const int* in_sizes, int n_in,
                              void* d_out, int out_size, void* d_ws, size_t ws_size,
                              hipStream_t stream) {
    const float* vis   = (const float*)d_in[0];
    const float* lab   = (const float*)d_in[1];
    const float* adj   = (const float*)d_in[2];
    const float* Wm    = (const float*)d_in[3];
    const float* a_src = (const float*)d_in[4];
    const float* a_dst = (const float*)d_in[5];
    const float* pq    = (const float*)d_in[6];
    const float* fcW   = (const float*)d_in[7];
    const float* fcb   = (const float*)d_in[8];
    float* out = (float*)d_out;

    char* w = (char*)d_ws;
    float* wh_lab = (float*)w;  w += (size_t)NN * HF * 4;    // 2 MB
    float* wh_vis = (float*)w;  w += (size_t)BB * HF * 4;
    float* es_lab = (float*)w;  w += (size_t)NN * HH * 4;
    float* ed_lab = (float*)w;  w += (size_t)NN * HH * 4;
    float* es_vis = (float*)w;  w += (size_t)BB * HH * 4;
    float* ed_vis = (float*)w;  w += (size_t)BB * HH * 4;
    int*   nlist  = (int*)w;    w += (size_t)NN * NN * 4;    // 4 MB
    int*   ncnt   = (int*)w;    w += (size_t)NN * 4;
    float* xout   = (float*)w;  w += (size_t)BB * NN * HF * 4;  // 16 MB
    float* scores = (float*)w;  w += (size_t)BB * NN * 4;

    k_wh_lab<<<NN, 256, 0, stream>>>(lab, Wm, a_src, a_dst, wh_lab, es_lab, ed_lab);
    k_wh_vis<<<BB, 256, 0, stream>>>(vis, Wm, a_src, a_dst, wh_vis, es_vis, ed_vis);
    k_compact<<<NN, 256, 0, stream>>>(adj, nlist, ncnt);
    k_attn<<<dim3(NN, BB), 256, 0, stream>>>(wh_lab, wh_vis, es_lab, ed_lab, es_vis, ed_vis,
                                             nlist, ncnt, pq, xout, scores);
    k_pool_fc<<<BB, 256, 0, stream>>>(xout, scores, fcW, fcb, out);
}

// Round 3
// 132.156 us; speedup vs baseline: 2.0384x; 2.0384x over previous
//
#include <hip/hip_runtime.h>

#define NN 1024
#define BB 8
#define HH 8
#define FF 64
#define HF 512
#define D_LAB 256
#define D_VIS 512
#define KT 128

// ---------------- Kernel 1: Wh_lab (4 nodes/block) + per-node e_src/e_dst
__global__ void __launch_bounds__(256) k_wh_lab(const float* __restrict__ lab,
    const float* __restrict__ Wm, const float* __restrict__ a_src, const float* __restrict__ a_dst,
    float* __restrict__ wh, float* __restrict__ es, float* __restrict__ ed)
{
    int n0 = blockIdx.x * 4, t = threadIdx.x;
    __shared__ float xs[4][D_LAB];
    __shared__ float whs[4][HF];
    #pragma unroll
    for (int nd = 0; nd < 4; ++nd) xs[nd][t] = lab[(n0 + nd) * D_LAB + t];
    __syncthreads();
    float a00=0.f,a01=0.f,a10=0.f,a11=0.f,a20=0.f,a21=0.f,a30=0.f,a31=0.f;
    #pragma unroll 2
    for (int i = 0; i < D_LAB; ++i) {
        float w0 = Wm[i * HF + t], w1 = Wm[i * HF + t + 256];
        float x0 = xs[0][i], x1 = xs[1][i], x2 = xs[2][i], x3 = xs[3][i];
        a00 += x0 * w0; a01 += x0 * w1;
        a10 += x1 * w0; a11 += x1 * w1;
        a20 += x2 * w0; a21 += x2 * w1;
        a30 += x3 * w0; a31 += x3 * w1;
    }
    wh[(n0+0)*HF + t] = a00; wh[(n0+0)*HF + t + 256] = a01;
    wh[(n0+1)*HF + t] = a10; wh[(n0+1)*HF + t + 256] = a11;
    wh[(n0+2)*HF + t] = a20; wh[(n0+2)*HF + t + 256] = a21;
    wh[(n0+3)*HF + t] = a30; wh[(n0+3)*HF + t + 256] = a31;
    whs[0][t] = a00; whs[0][t+256] = a01;
    whs[1][t] = a10; whs[1][t+256] = a11;
    whs[2][t] = a20; whs[2][t+256] = a21;
    whs[3][t] = a30; whs[3][t+256] = a31;
    __syncthreads();
    // 64 tasks (nd,h,src/dst) x 4 threads each (16 f per thread)
    int task = t >> 2, sub = t & 3;
    int nd = task >> 4, rest = task & 15, h = rest >> 1, sd = rest & 1;
    const float* av = (sd ? a_dst : a_src) + h * FF;
    const float* wr = whs[nd] + h * FF;
    float s = 0.f;
    int fb = sub * 16;
    #pragma unroll
    for (int f = 0; f < 16; ++f) s += wr[fb + f] * av[fb + f];
    s += __shfl_down(s, 2); s += __shfl_down(s, 1);
    if (sub == 0) (sd ? ed : es)[(n0 + nd) * HH + h] = s;
}

// ---------------- Kernel 2: Wh_vis partial (k-chunks, atomic into zeroed whv)
__global__ void __launch_bounds__(256) k_wh_vis_part(const float* __restrict__ vis,
    const float* __restrict__ Wm, float* __restrict__ whv)
{
    int q = blockIdx.x, b = blockIdx.y, t = threadIdx.x;
    __shared__ float xs[128];
    if (t < 128) xs[t] = vis[b * D_VIS + q * 128 + t];
    __syncthreads();
    float a0 = 0.f, a1 = 0.f;
    #pragma unroll 2
    for (int ii = 0; ii < 128; ++ii) {
        float xv = xs[ii];
        const float* wr = Wm + (size_t)(D_LAB + q * 128 + ii) * HF;
        a0 += xv * wr[t]; a1 += xv * wr[t + 256];
    }
    atomicAdd(&whv[b * HF + t], a0);
    atomicAdd(&whv[b * HF + t + 256], a1);
}

// ---------------- Kernel 3: deterministic adjacency compaction (1 wave/row)
__global__ void k_compact(const float* __restrict__ adj, int* __restrict__ list,
                          int* __restrict__ cnt)
{
    int i = blockIdx.x, lane = threadIdx.x; // 64 threads
    int base = 0;
    for (int c = 0; c < 16; ++c) {
        int j = c * 64 + lane;
        bool pres = adj[(size_t)i * NN + j] > 0.f;
        unsigned long long m = __ballot(pres);
        int pos = __popcll(m & ((1ull << lane) - 1ull));
        if (pres) list[(size_t)i * NN + base + pos] = j;
        base += __popcll(m);
    }
    if (lane == 0) cnt[i] = base;
}

// ---------------- Kernel 4: fused all-batch GAT attention per node
__global__ void __launch_bounds__(256) k_attn(
    const float* __restrict__ wh_lab,   // (N, 512)
    const float* __restrict__ whv,      // (B, 512)
    const float* __restrict__ es_lab,   // (N, 8)
    const float* __restrict__ ed_lab,   // (N, 8)
    const float* __restrict__ a_src, const float* __restrict__ a_dst,
    const int* __restrict__ list, const int* __restrict__ cnt,
    const float* __restrict__ pool_q,
    float* __restrict__ xout,           // (B, N, 512)
    float* __restrict__ scores)         // (B, N)
{
    int i = blockIdx.x, t = threadIdx.x;
    int lane = t & 63, wid = t >> 6;
    int nn = cnt[i];

    __shared__ float att[KT * 64];      // [k][h][b] 32 KB
    __shared__ int jl[KT];
    __shared__ float base_s[64];        // per (b,h): es_lab[i,h]+es_vis[b,h]+ed_vis[b,h]
    __shared__ float mx_s[64], inv_s[64];
    __shared__ float red[4][64];
    __shared__ float red2[4][BB];

    // base_s: t<64 -> b=t>>3, h=t&7; es_vis+ed_vis computed from whv on the fly
    if (t < 64) {
        int b = t >> 3, h = t & 7;
        const float* wr = whv + b * HF + h * FF;
        const float* as = a_src + h * FF;
        const float* ad = a_dst + h * FF;
        float s = 0.f;
        #pragma unroll 8
        for (int f = 0; f < FF; ++f) s += wr[f] * (as[f] + ad[f]);
        base_s[t] = s + es_lab[i * HH + h];
    }
    __syncthreads();

    int p = lane;               // pair id for phases A/B (b=p>>3, h=p&7)
    int ph = p & 7;
    float basev = base_s[p];

    // ---- Phase A: global max per (b,h)
    float mx = -1e30f;
    for (int c0 = 0; c0 < nn; c0 += KT) {
        int kc = min(KT, nn - c0);
        __syncthreads();
        if (t < kc) jl[t] = list[(size_t)i * NN + c0 + t];
        __syncthreads();
        for (int k = wid; k < kc; k += 4) {
            int j = jl[k];
            float e = basev + ed_lab[j * HH + ph];
            e = e > 0.f ? e : 0.2f * e;
            mx = fmaxf(mx, e);
        }
    }
    red[wid][lane] = mx;
    __syncthreads();
    if (t < 64) mx_s[t] = fmaxf(fmaxf(red[0][t], red[1][t]), fmaxf(red[2][t], red[3][t]));
    __syncthreads();

    float mxv = mx_s[p];
    int attw = (p & 7) * 8 + (p >> 3);   // write slot [h][b] within a k-row

    // ---- Phases B+C per chunk
    float ssum = 0.f;
    float c00=0.f,c01=0.f,c10=0.f,c11=0.f,c20=0.f,c21=0.f,c30=0.f,c31=0.f;
    float c40=0.f,c41=0.f,c50=0.f,c51=0.f,c60=0.f,c61=0.f,c70=0.f,c71=0.f;
    int f0 = 2 * t;              // two features per thread
    int h8 = (t >> 5) * 8;       // head block offset within att k-row

    for (int c0 = 0; c0 < nn; c0 += KT) {
        int kc = min(KT, nn - c0);
        __syncthreads();
        if (t < kc) jl[t] = list[(size_t)i * NN + c0 + t];
        __syncthreads();
        // B: exp + store att + partial sum
        for (int k = wid; k < kc; k += 4) {
            int j = jl[k];
            float e = basev + ed_lab[j * HH + ph];
            e = e > 0.f ? e : 0.2f * e;
            float pe = __expf(e - mxv);
            ssum += pe;
            att[k * 64 + attw] = pe;
        }
        __syncthreads();
        // C: aggregate 8 batches x 2 feats
        #pragma unroll 4
        for (int k = 0; k < kc; ++k) {
            int j = jl[k];
            const float2 r = *(const float2*)&wh_lab[(size_t)j * HF + f0];
            const float4 aA = *(const float4*)&att[k * 64 + h8];
            const float4 aB = *(const float4*)&att[k * 64 + h8 + 4];
            c00 += aA.x * r.x; c01 += aA.x * r.y;
            c10 += aA.y * r.x; c11 += aA.y * r.y;
            c20 += aA.z * r.x; c21 += aA.z * r.y;
            c30 += aA.w * r.x; c31 += aA.w * r.y;
            c40 += aB.x * r.x; c41 += aB.x * r.y;
            c50 += aB.y * r.x; c51 += aB.y * r.y;
            c60 += aB.z * r.x; c61 += aB.z * r.y;
            c70 += aB.w * r.x; c71 += aB.w * r.y;
        }
    }
    // reduce sums -> inv
    __syncthreads();
    red[wid][lane] = ssum;
    __syncthreads();
    if (t < 64) inv_s[t] = 1.0f / (red[0][t] + red[1][t] + red[2][t] + red[3][t]);
    __syncthreads();

    // ---- epilogue: normalize, add Wh_vis, ELU, store, pooling score partials
    int h_t = t >> 5;
    const float2 pqv = *(const float2*)&pool_q[f0];
    float acc0[8] = {c00,c10,c20,c30,c40,c50,c60,c70};
    float acc1[8] = {c01,c11,c21,c31,c41,c51,c61,c71};
    #pragma unroll
    for (int b = 0; b < BB; ++b) {
        float iv = inv_s[b * 8 + h_t];
        const float2 wv = *(const float2*)&whv[b * HF + f0];
        float o0 = acc0[b] * iv + wv.x;
        float o1 = acc1[b] * iv + wv.y;
        o0 = o0 > 0.f ? o0 : (__expf(o0) - 1.f);
        o1 = o1 > 0.f ? o1 : (__expf(o1) - 1.f);
        float2 ov; ov.x = o0; ov.y = o1;
        *(float2*)&xout[((size_t)b * NN + i) * HF + f0] = ov;
        float sp = o0 * pqv.x + o1 * pqv.y;
        #pragma unroll
        for (int off = 32; off > 0; off >>= 1) sp += __shfl_down(sp, off);
        if (lane == 0) red2[wid][b] = sp;
    }
    __syncthreads();
    if (t < BB)
        scores[t * NN + i] = red2[0][t] + red2[1][t] + red2[2][t] + red2[3][t];
}

// ---------------- Kernel 5: per-batch score softmax (in-place normalize)
__global__ void __launch_bounds__(256) k_smax(float* __restrict__ sc)
{
    int b = blockIdx.x, t = threadIdx.x, lane = t & 63, wid = t >> 6;
    __shared__ float red[4];
    __shared__ float sM, sI;
    float v[4];
    float mx = -1e30f;
    #pragma unroll
    for (int q = 0; q < 4; ++q) { v[q] = sc[b * NN + q * 256 + t]; mx = fmaxf(mx, v[q]); }
    #pragma unroll
    for (int off = 32; off > 0; off >>= 1) mx = fmaxf(mx, __shfl_down(mx, off));
    if (lane == 0) red[wid] = mx;
    __syncthreads();
    if (t == 0) sM = fmaxf(fmaxf(red[0], red[1]), fmaxf(red[2], red[3]));
    __syncthreads();
    float sm = 0.f;
    #pragma unroll
    for (int q = 0; q < 4; ++q) { v[q] = __expf(v[q] - sM); sm += v[q]; }
    #pragma unroll
    for (int off = 32; off > 0; off >>= 1) sm += __shfl_down(sm, off);
    __syncthreads();
    if (lane == 0) red[wid] = sm;
    __syncthreads();
    if (t == 0) sI = 1.0f / (red[0] + red[1] + red[2] + red[3]);
    __syncthreads();
    #pragma unroll
    for (int q = 0; q < 4; ++q) sc[b * NN + q * 256 + t] = v[q] * sI;
}

// ---------------- Kernel 6: pooling partials (atomic into zeroed pooled)
__global__ void __launch_bounds__(256) k_pool(const float* __restrict__ xout,
    const float* __restrict__ wn, float* __restrict__ pooled)
{
    int q = blockIdx.x, b = blockIdx.y, t = threadIdx.x;
    __shared__ float wl[64];
    if (t < 64) wl[t] = wn[b * NN + q * 64 + t];
    __syncthreads();
    int f0 = 2 * t;
    float ax = 0.f, ay = 0.f;
    #pragma unroll 4
    for (int n = 0; n < 64; ++n) {
        float w = wl[n];
        const float2 r = *(const float2*)&xout[((size_t)b * NN + q * 64 + n) * HF + f0];
        ax += w * r.x; ay += w * r.y;
    }
    atomicAdd(&pooled[b * HF + f0], ax);
    atomicAdd(&pooled[b * HF + f0 + 1], ay);
}

// ---------------- Kernel 7: FC (k-quarters, atomic into zeroed out; bias at q==0)
__global__ void __launch_bounds__(256) k_fc(const float* __restrict__ pooled,
    const float* __restrict__ fc_W, const float* __restrict__ fc_b, float* __restrict__ out)
{
    int q = blockIdx.x, b = blockIdx.y, t = threadIdx.x;
    __shared__ float pl[128];
    if (t < 128) pl[t] = pooled[b * HF + q * 128 + t];
    __syncthreads();
    int f0 = 2 * t;
    float ax = 0.f, ay = 0.f;
    if (q == 0) { ax = fc_b[f0]; ay = fc_b[f0 + 1]; }
    #pragma unroll 4
    for (int kk = 0; kk < 128; ++kk) {
        float pv = pl[kk];
        const float2 wv = *(const float2*)&fc_W[(size_t)(q * 128 + kk) * HF + f0];
        ax += pv * wv.x; ay += pv * wv.y;
    }
    atomicAdd(&out[b * HF + f0], ax);
    atomicAdd(&out[b * HF + f0 + 1], ay);
}

extern "C" void kernel_launch(void* const* d_in, const int* in_sizes, int n_in,
                              void* d_out, int out_size, void* d_ws, size_t ws_size,
                              hipStream_t stream) {
    const float* vis   = (const float*)d_in[0];
    const float* lab   = (const float*)d_in[1];
    const float* adj   = (const float*)d_in[2];
    const float* Wm    = (const float*)d_in[3];
    const float* a_src = (const float*)d_in[4];
    const float* a_dst = (const float*)d_in[5];
    const float* pq    = (const float*)d_in[6];
    const float* fcW   = (const float*)d_in[7];
    const float* fcb   = (const float*)d_in[8];
    float* out = (float*)d_out;

    char* w = (char*)d_ws;
    float* whv    = (float*)w;  w += (size_t)BB * HF * 4;     // 16 KB (zeroed)
    float* pooled = (float*)w;  w += (size_t)BB * HF * 4;     // 16 KB (zeroed)
    float* wh_lab = (float*)w;  w += (size_t)NN * HF * 4;     // 2 MB
    float* es_lab = (float*)w;  w += (size_t)NN * HH * 4;
    float* ed_lab = (float*)w;  w += (size_t)NN * HH * 4;
    int*   nlist  = (int*)w;    w += (size_t)NN * NN * 4;     // 4 MB
    int*   ncnt   = (int*)w;    w += (size_t)NN * 4;
    float* xout   = (float*)w;  w += (size_t)BB * NN * HF * 4; // 16 MB
    float* scores = (float*)w;  w += (size_t)BB * NN * 4;     // reused as wn (in-place)

    hipMemsetAsync(whv, 0, 2 * (size_t)BB * HF * 4, stream);  // whv + pooled
    hipMemsetAsync(out, 0, (size_t)BB * HF * 4, stream);

    k_wh_lab<<<NN / 4, 256, 0, stream>>>(lab, Wm, a_src, a_dst, wh_lab, es_lab, ed_lab);
    k_wh_vis_part<<<dim3(4, BB), 256, 0, stream>>>(vis, Wm, whv);
    k_compact<<<NN, 64, 0, stream>>>(adj, nlist, ncnt);
    k_attn<<<NN, 256, 0, stream>>>(wh_lab, whv, es_lab, ed_lab, a_src, a_dst,
                                   nlist, ncnt, pq, xout, scores);
    k_smax<<<BB, 256, 0, stream>>>(scores);
    k_pool<<<dim3(16, BB), 256, 0, stream>>>(xout, scores, pooled);
    k_fc<<<dim3(4, BB), 256, 0, stream>>>(pooled, fcW, fcb, out);
}

// Round 4
// 105.046 us; speedup vs baseline: 2.5644x; 1.2581x over previous
//
#include <hip/hip_runtime.h>

#define NN 1024
#define BB 8
#define HH 8
#define FF 64
#define HF 512
#define KT 128

__device__ __forceinline__ unsigned fkey(float x) {
    unsigned u = __float_as_uint(x);
    return (u & 0x80000000u) ? ~u : (u | 0x80000000u);
}
__device__ __forceinline__ float fdec(unsigned k) {
    return (k & 0x80000000u) ? __uint_as_float(k ^ 0x80000000u) : __uint_as_float(~k);
}

// ---------------- K1: fused prep: wh_lab GEMM (4 nodes x K-half, det. 2-way atomic),
//                  whv (2-way atomic), P projection, adjacency compaction
__global__ void __launch_bounds__(256) k_prep(
    const float* __restrict__ lab, const float* __restrict__ vis,
    const float* __restrict__ adj, const float* __restrict__ Wm,
    const float* __restrict__ a_src, const float* __restrict__ a_dst,
    float* __restrict__ wh, float* __restrict__ whv, float* __restrict__ P,
    int* __restrict__ list, int* __restrict__ cnt)
{
    int bx = blockIdx.x, t = threadIdx.x;
    __shared__ float sh[512];
    if (bx < 512) {
        // wh_lab: nodes n0..n0+3, K rows kh*128..+127
        int np = bx >> 1, kh = bx & 1, n0 = np * 4;
        for (int u = t; u < 512; u += 256)
            sh[u] = lab[(n0 + (u >> 7)) * 256 + kh * 128 + (u & 127)];
        __syncthreads();
        float a00=0,a01=0,a10=0,a11=0,a20=0,a21=0,a30=0,a31=0;
        const float* wp = Wm + (size_t)(kh * 128) * HF;
        #pragma unroll 8
        for (int i = 0; i < 128; ++i) {
            float w0 = wp[i * HF + t], w1 = wp[i * HF + t + 256];
            float x0 = sh[i], x1 = sh[128 + i], x2 = sh[256 + i], x3 = sh[384 + i];
            a00 += x0*w0; a01 += x0*w1; a10 += x1*w0; a11 += x1*w1;
            a20 += x2*w0; a21 += x2*w1; a30 += x3*w0; a31 += x3*w1;
        }
        atomicAdd(&wh[(n0+0)*HF + t], a00); atomicAdd(&wh[(n0+0)*HF + t + 256], a01);
        atomicAdd(&wh[(n0+1)*HF + t], a10); atomicAdd(&wh[(n0+1)*HF + t + 256], a11);
        atomicAdd(&wh[(n0+2)*HF + t], a20); atomicAdd(&wh[(n0+2)*HF + t + 256], a21);
        atomicAdd(&wh[(n0+3)*HF + t], a30); atomicAdd(&wh[(n0+3)*HF + t + 256], a31);
    } else if (bx < 528) {
        // P[i][c]: c = h*2+sd; dot over f of W[i, h*64+f] * a_{src/dst}[h,f]
        int ib = bx - 512;
        int i = ib * 16 + (t >> 4), c = t & 15, h = c >> 1;
        const float* av = ((c & 1) ? a_dst : a_src) + h * FF;
        const float* wr = Wm + (size_t)i * HF + h * FF;
        float s = 0.f;
        #pragma unroll
        for (int f = 0; f < FF; ++f) s += wr[f] * av[f];
        P[i * 16 + c] = s;
    } else if (bx < 544) {
        // whv: batch b, K rows 256 + kh*256 ..
        int id = bx - 528, kh = id & 1, b = id >> 1;
        if (t < 256) sh[t] = vis[b * 512 + kh * 256 + t];
        __syncthreads();
        float a0 = 0.f, a1 = 0.f;
        const float* wp = Wm + (size_t)(256 + kh * 256) * HF;
        #pragma unroll 4
        for (int i = 0; i < 256; ++i) {
            float xv = sh[i];
            a0 += xv * wp[i * HF + t];
            a1 += xv * wp[i * HF + t + 256];
        }
        atomicAdd(&whv[b * HF + t], a0);
        atomicAdd(&whv[b * HF + t + 256], a1);
    } else {
        // adjacency compaction: 4 rows/block, one wave per row (deterministic ballot)
        int id = bx - 544;
        int i = id * 4 + (t >> 6), lane = t & 63;
        int base = 0;
        for (int c = 0; c < 16; ++c) {
            int j = c * 64 + lane;
            bool pres = adj[(size_t)i * NN + j] > 0.f;
            unsigned long long m = __ballot(pres);
            int pos = __popcll(m & ((1ull << lane) - 1ull));
            if (pres) list[i * NN + base + pos] = j;
            base += __popcll(m);
        }
        if (lane == 0) cnt[i] = base;
    }
}

// ---------------- K2: es/ed = lab @ P (+ global edmax keys), bv[b,h] = whv.(a_src+a_dst)
__global__ void __launch_bounds__(256) k_prep2(
    const float* __restrict__ lab, const float* __restrict__ P,
    const float* __restrict__ whv,
    const float* __restrict__ a_src, const float* __restrict__ a_dst,
    float* __restrict__ es, float* __restrict__ ed,
    unsigned* __restrict__ edmax_key, float* __restrict__ bv)
{
    int bx = blockIdx.x, t = threadIdx.x;
    if (bx < 64) {
        __shared__ float labS[16 * 256];
        __shared__ float edsh[16][8];
        int n0 = bx * 16;
        for (int u = t; u < 4096; u += 256)
            labS[u] = lab[(n0 + (u >> 8)) * 256 + (u & 255)];
        __syncthreads();
        int nd = t >> 4, c = t & 15, h = c >> 1, sd = c & 1;
        const float* xr = labS + nd * 256;
        float s = 0.f;
        #pragma unroll 8
        for (int i = 0; i < 256; ++i) s += xr[i] * P[i * 16 + c];
        int n = n0 + nd;
        if (sd) { ed[n * 8 + h] = s; edsh[nd][h] = s; }
        else es[n * 8 + h] = s;
        __syncthreads();
        if (t < 8) {
            float m = -1e30f;
            #pragma unroll
            for (int q = 0; q < 16; ++q) m = fmaxf(m, edsh[q][t]);
            atomicMax(&edmax_key[t], fkey(m));
        }
    } else if (t < 64) {
        int b = t >> 3, h = t & 7;
        const float* wr = whv + b * HF + h * FF;
        const float* as = a_src + h * FF;
        const float* ad = a_dst + h * FF;
        float s = 0.f;
        #pragma unroll 8
        for (int f = 0; f < FF; ++f) s += wr[f] * (as[f] + ad[f]);
        bv[t] = s;   // t = b*8+h
    }
}

// ---------------- K3: attention, feature-half split (z), upper-bound shift (no max pass)
__global__ void __launch_bounds__(256) k_attn(
    const float* __restrict__ wh, const float* __restrict__ whv,
    const float* __restrict__ es, const float* __restrict__ ed,
    const unsigned* __restrict__ edmax_key, const float* __restrict__ bv,
    const int* __restrict__ list, const int* __restrict__ cnt,
    const float* __restrict__ pool_q,
    float* __restrict__ xout, float* __restrict__ scores_half)
{
    int i = blockIdx.x, z = blockIdx.y, t = threadIdx.x;
    int lane = t & 63, wid = t >> 6;
    int nn = cnt[i];

    __shared__ float att[KT * 32];     // [k][hl*8+b] 16 KB
    __shared__ int jl[KT];
    __shared__ float base_s[32], M_s[32], inv_s[32];
    __shared__ float red[8][32];
    __shared__ float red2[4][BB];

    if (t < 32) {
        int hl = t >> 3, b = t & 7, h = z * 4 + hl;
        float base = es[i * 8 + h] + bv[b * 8 + h];
        base_s[t] = base;
        float mv = base + fdec(edmax_key[h]);   // >= any neighbor's pre-leaky e
        M_s[t] = mv > 0.f ? mv : 0.2f * mv;     // leaky is monotone -> valid upper bound
    }
    __syncthreads();

    int p = t & 31;
    int hp = z * 4 + (p >> 3);
    float basev = base_s[p], Mv = M_s[p];
    float ssum = 0.f;
    float ac0=0,ac1=0,ac2=0,ac3=0,ac4=0,ac5=0,ac6=0,ac7=0;
    int hl8 = (t >> 6) * 8;
    int fg = z * 256 + t;

    for (int c0 = 0; c0 < nn; c0 += KT) {
        int kc = min(KT, nn - c0);
        __syncthreads();
        if (t < kc) jl[t] = list[i * NN + c0 + t];
        __syncthreads();
        for (int k = t >> 5; k < kc; k += 8) {
            int j = jl[k];
            float e = basev + ed[j * 8 + hp];
            e = e > 0.f ? e : 0.2f * e;
            float pe = __expf(e - Mv);
            ssum += pe;
            att[k * 32 + p] = pe;
        }
        __syncthreads();
        #pragma unroll 2
        for (int k = 0; k < kc; ++k) {
            float r = wh[jl[k] * HF + fg];
            const float4 aA = *(const float4*)&att[k * 32 + hl8];
            const float4 aB = *(const float4*)&att[k * 32 + hl8 + 4];
            ac0 += aA.x * r; ac1 += aA.y * r; ac2 += aA.z * r; ac3 += aA.w * r;
            ac4 += aB.x * r; ac5 += aB.y * r; ac6 += aB.z * r; ac7 += aB.w * r;
        }
    }
    __syncthreads();
    red[t >> 5][p] = ssum;
    __syncthreads();
    if (t < 32) {
        float s = 0.f;
        #pragma unroll
        for (int g = 0; g < 8; ++g) s += red[g][t];
        inv_s[t] = 1.0f / s;
    }
    __syncthreads();

    int hl = t >> 6;
    float pqv = pool_q[fg];
    float accs[8] = {ac0,ac1,ac2,ac3,ac4,ac5,ac6,ac7};
    #pragma unroll
    for (int b = 0; b < BB; ++b) {
        float o = accs[b] * inv_s[hl * 8 + b] + whv[b * HF + fg];
        o = o > 0.f ? o : (__expf(o) - 1.f);
        xout[(b * NN + i) * HF + fg] = o;
        float sp = o * pqv;
        #pragma unroll
        for (int off = 32; off > 0; off >>= 1) sp += __shfl_down(sp, off);
        if (lane == 0) red2[wid][b] = sp;
    }
    __syncthreads();
    if (t < BB)
        scores_half[(z * BB + t) * NN + i] = red2[0][t] + red2[1][t] + red2[2][t] + red2[3][t];
}

// ---------------- K4: per-batch node softmax -> normalized weights
__global__ void __launch_bounds__(256) k_smax(const float* __restrict__ sh2,
                                              float* __restrict__ wn)
{
    int b = blockIdx.x, t = threadIdx.x, lane = t & 63, wid = t >> 6;
    __shared__ float red[4];
    __shared__ float sM, sI;
    float v[4];
    float mx = -1e30f;
    #pragma unroll
    for (int q = 0; q < 4; ++q) {
        int n = q * 256 + t;
        v[q] = sh2[b * NN + n] + sh2[(BB + b) * NN + n];
        mx = fmaxf(mx, v[q]);
    }
    #pragma unroll
    for (int off = 32; off > 0; off >>= 1) mx = fmaxf(mx, __shfl_down(mx, off));
    if (lane == 0) red[wid] = mx;
    __syncthreads();
    if (t == 0) sM = fmaxf(fmaxf(red[0], red[1]), fmaxf(red[2], red[3]));
    __syncthreads();
    float sm = 0.f;
    #pragma unroll
    for (int q = 0; q < 4; ++q) { v[q] = __expf(v[q] - sM); sm += v[q]; }
    #pragma unroll
    for (int off = 32; off > 0; off >>= 1) sm += __shfl_down(sm, off);
    __syncthreads();
    if (lane == 0) red[wid] = sm;
    __syncthreads();
    if (t == 0) sI = 1.0f / (red[0] + red[1] + red[2] + red[3]);
    __syncthreads();
    #pragma unroll
    for (int q = 0; q < 4; ++q) wn[b * NN + q * 256 + t] = v[q] * sI;
}

// ---------------- K5: pooling partials (atomic into zeroed pooled)
__global__ void __launch_bounds__(256) k_pool(const float* __restrict__ xout,
    const float* __restrict__ wn, float* __restrict__ pooled)
{
    int q = blockIdx.x, b = blockIdx.y, t = threadIdx.x;
    __shared__ float wl[64];
    if (t < 64) wl[t] = wn[b * NN + q * 64 + t];
    __syncthreads();
    int f0 = 2 * t;
    float ax = 0.f, ay = 0.f;
    #pragma unroll 4
    for (int n = 0; n < 64; ++n) {
        float w = wl[n];
        const float2 r = *(const float2*)&xout[((b * NN + q * 64 + n)) * HF + f0];
        ax += w * r.x; ay += w * r.y;
    }
    atomicAdd(&pooled[b * HF + f0], ax);
    atomicAdd(&pooled[b * HF + f0 + 1], ay);
}

// ---------------- K6: FC (k-quarters, atomic into zeroed out; bias at q==0)
__global__ void __launch_bounds__(256) k_fc(const float* __restrict__ pooled,
    const float* __restrict__ fc_W, const float* __restrict__ fc_b,
    float* __restrict__ out)
{
    int q = blockIdx.x, b = blockIdx.y, t = threadIdx.x;
    __shared__ float pl[128];
    if (t < 128) pl[t] = pooled[b * HF + q * 128 + t];
    __syncthreads();
    int f0 = 2 * t;
    float ax = 0.f, ay = 0.f;
    if (q == 0) { ax = fc_b[f0]; ay = fc_b[f0 + 1]; }
    #pragma unroll 4
    for (int kk = 0; kk < 128; ++kk) {
        float pv = pl[kk];
        const float2 wv = *(const float2*)&fc_W[(q * 128 + kk) * HF + f0];
        ax += pv * wv.x; ay += pv * wv.y;
    }
    atomicAdd(&out[b * HF + f0], ax);
    atomicAdd(&out[b * HF + f0 + 1], ay);
}

extern "C" void kernel_launch(void* const* d_in, const int* in_sizes, int n_in,
                              void* d_out, int out_size, void* d_ws, size_t ws_size,
                              hipStream_t stream) {
    const float* vis   = (const float*)d_in[0];
    const float* lab   = (const float*)d_in[1];
    const float* adj   = (const float*)d_in[2];
    const float* Wm    = (const float*)d_in[3];
    const float* a_src = (const float*)d_in[4];
    const float* a_dst = (const float*)d_in[5];
    const float* pq    = (const float*)d_in[6];
    const float* fcW   = (const float*)d_in[7];
    const float* fcb   = (const float*)d_in[8];
    float* out = (float*)d_out;

    char* w = (char*)d_ws;
    // ---- zero region (one memset): wh, whv, pooled, edmax ----
    float*    wh     = (float*)w;    w += (size_t)NN * HF * 4;      // 2 MB
    float*    whv    = (float*)w;    w += (size_t)BB * HF * 4;      // 16 KB
    float*    pooled = (float*)w;    w += (size_t)BB * HF * 4;      // 16 KB
    unsigned* edmax  = (unsigned*)w; w += 256;                       // 8 keys + pad
    size_t zbytes = (size_t)NN * HF * 4 + 2 * (size_t)BB * HF * 4 + 256;
    // ---- plain-store region ----
    float* P      = (float*)w;  w += 256 * 16 * 4;                  // 16 KB
    float* bv     = (float*)w;  w += 64 * 4;
    float* es     = (float*)w;  w += (size_t)NN * HH * 4;
    float* ed     = (float*)w;  w += (size_t)NN * HH * 4;
    int*   nlist  = (int*)w;    w += (size_t)NN * NN * 4;           // 4 MB
    int*   ncnt   = (int*)w;    w += (size_t)NN * 4;
    float* xout   = (float*)w;  w += (size_t)BB * NN * HF * 4;      // 16 MB
    float* sch    = (float*)w;  w += (size_t)2 * BB * NN * 4;       // 64 KB
    float* wn     = (float*)w;  w += (size_t)BB * NN * 4;           // 32 KB

    hipMemsetAsync(wh, 0, zbytes, stream);
    hipMemsetAsync(out, 0, (size_t)BB * HF * 4, stream);

    k_prep<<<800, 256, 0, stream>>>(lab, vis, adj, Wm, a_src, a_dst,
                                    wh, whv, P, nlist, ncnt);
    k_prep2<<<65, 256, 0, stream>>>(lab, P, whv, a_src, a_dst, es, ed, edmax, bv);
    k_attn<<<dim3(NN, 2), 256, 0, stream>>>(wh, whv, es, ed, edmax, bv,
                                            nlist, ncnt, pq, xout, sch);
    k_smax<<<BB, 256, 0, stream>>>(sch, wn);
    k_pool<<<dim3(16, BB), 256, 0, stream>>>(xout, wn, pooled);
    k_fc<<<dim3(4, BB), 256, 0, stream>>>(pooled, fcW, fcb, out);
}

// Round 5
// 103.617 us; speedup vs baseline: 2.5998x; 1.0138x over previous
//
#include <hip/hip_runtime.h>

#define NN 1024
#define BB 8
#define HH 8
#define FF 64
#define HF 512
#define KT 128

__device__ __forceinline__ unsigned fkey(float x) {
    unsigned u = __float_as_uint(x);
    return (u & 0x80000000u) ? ~u : (u | 0x80000000u);
}
__device__ __forceinline__ float fdec(unsigned k) {
    return (k & 0x80000000u) ? __uint_as_float(k ^ 0x80000000u) : __uint_as_float(~k);
}

// ---------------- K0: fast zero of workspace zero-region + out
__global__ void __launch_bounds__(256) k_zero(float4* __restrict__ pa, int na4,
                                              float4* __restrict__ pb, int nb4)
{
    int idx = blockIdx.x * 256 + threadIdx.x;
    int stride = gridDim.x * 256;
    float4 z; z.x = 0.f; z.y = 0.f; z.z = 0.f; z.w = 0.f;
    for (int i = idx; i < na4; i += stride) pa[i] = z;
    for (int i = idx; i < nb4; i += stride) pb[i] = z;
}

// ---------------- K1: fused prep: wh_lab GEMM (4 nodes x K-half, det. 2-way atomic),
//                  whv (2-way atomic), P projection, adjacency compaction
__global__ void __launch_bounds__(256) k_prep(
    const float* __restrict__ lab, const float* __restrict__ vis,
    const float* __restrict__ adj, const float* __restrict__ Wm,
    const float* __restrict__ a_src, const float* __restrict__ a_dst,
    float* __restrict__ wh, float* __restrict__ whv, float* __restrict__ P,
    int* __restrict__ list, int* __restrict__ cnt)
{
    int bx = blockIdx.x, t = threadIdx.x;
    __shared__ float sh[512];
    if (bx < 512) {
        // wh_lab: nodes n0..n0+3, K rows kh*128..+127
        int np = bx >> 1, kh = bx & 1, n0 = np * 4;
        for (int u = t; u < 512; u += 256)
            sh[u] = lab[(n0 + (u >> 7)) * 256 + kh * 128 + (u & 127)];
        __syncthreads();
        float a00=0,a01=0,a10=0,a11=0,a20=0,a21=0,a30=0,a31=0;
        const float* wp = Wm + (size_t)(kh * 128) * HF;
        #pragma unroll 8
        for (int i = 0; i < 128; ++i) {
            float w0 = wp[i * HF + t], w1 = wp[i * HF + t + 256];
            float x0 = sh[i], x1 = sh[128 + i], x2 = sh[256 + i], x3 = sh[384 + i];
            a00 += x0*w0; a01 += x0*w1; a10 += x1*w0; a11 += x1*w1;
            a20 += x2*w0; a21 += x2*w1; a30 += x3*w0; a31 += x3*w1;
        }
        atomicAdd(&wh[(n0+0)*HF + t], a00); atomicAdd(&wh[(n0+0)*HF + t + 256], a01);
        atomicAdd(&wh[(n0+1)*HF + t], a10); atomicAdd(&wh[(n0+1)*HF + t + 256], a11);
        atomicAdd(&wh[(n0+2)*HF + t], a20); atomicAdd(&wh[(n0+2)*HF + t + 256], a21);
        atomicAdd(&wh[(n0+3)*HF + t], a30); atomicAdd(&wh[(n0+3)*HF + t + 256], a31);
    } else if (bx < 528) {
        // P[i][c]: c = h*2+sd; dot over f of W[i, h*64+f] * a_{src/dst}[h,f]
        int ib = bx - 512;
        int i = ib * 16 + (t >> 4), c = t & 15, h = c >> 1;
        const float* av = ((c & 1) ? a_dst : a_src) + h * FF;
        const float* wr = Wm + (size_t)i * HF + h * FF;
        float s = 0.f;
        #pragma unroll
        for (int f = 0; f < FF; ++f) s += wr[f] * av[f];
        P[i * 16 + c] = s;
    } else if (bx < 544) {
        // whv: batch b, K rows 256 + kh*256 ..
        int id = bx - 528, kh = id & 1, b = id >> 1;
        if (t < 256) sh[t] = vis[b * 512 + kh * 256 + t];
        __syncthreads();
        float a0 = 0.f, a1 = 0.f;
        const float* wp = Wm + (size_t)(256 + kh * 256) * HF;
        #pragma unroll 4
        for (int i = 0; i < 256; ++i) {
            float xv = sh[i];
            a0 += xv * wp[i * HF + t];
            a1 += xv * wp[i * HF + t + 256];
        }
        atomicAdd(&whv[b * HF + t], a0);
        atomicAdd(&whv[b * HF + t + 256], a1);
    } else {
        // adjacency compaction: 4 rows/block, one wave per row (deterministic ballot)
        int id = bx - 544;
        int i = id * 4 + (t >> 6), lane = t & 63;
        int base = 0;
        for (int c = 0; c < 16; ++c) {
            int j = c * 64 + lane;
            bool pres = adj[(size_t)i * NN + j] > 0.f;
            unsigned long long m = __ballot(pres);
            int pos = __popcll(m & ((1ull << lane) - 1ull));
            if (pres) list[i * NN + base + pos] = j;
            base += __popcll(m);
        }
        if (lane == 0) cnt[i] = base;
    }
}

// ---------------- K2: es/ed = lab @ P (+ global edmax keys), bv[b,h] = whv.(a_src+a_dst)
__global__ void __launch_bounds__(256) k_prep2(
    const float* __restrict__ lab, const float* __restrict__ P,
    const float* __restrict__ whv,
    const float* __restrict__ a_src, const float* __restrict__ a_dst,
    float* __restrict__ es, float* __restrict__ ed,
    unsigned* __restrict__ edmax_key, float* __restrict__ bv)
{
    int bx = blockIdx.x, t = threadIdx.x;
    if (bx < 64) {
        __shared__ float labS[16 * 256];
        __shared__ float edsh[16][8];
        int n0 = bx * 16;
        for (int u = t; u < 4096; u += 256)
            labS[u] = lab[(n0 + (u >> 8)) * 256 + (u & 255)];
        __syncthreads();
        int nd = t >> 4, c = t & 15, h = c >> 1, sd = c & 1;
        const float* xr = labS + nd * 256;
        float s = 0.f;
        #pragma unroll 8
        for (int i = 0; i < 256; ++i) s += xr[i] * P[i * 16 + c];
        int n = n0 + nd;
        if (sd) { ed[n * 8 + h] = s; edsh[nd][h] = s; }
        else es[n * 8 + h] = s;
        __syncthreads();
        if (t < 8) {
            float m = -1e30f;
            #pragma unroll
            for (int q = 0; q < 16; ++q) m = fmaxf(m, edsh[q][t]);
            atomicMax(&edmax_key[t], fkey(m));
        }
    } else if (t < 64) {
        int b = t >> 3, h = t & 7;
        const float* wr = whv + b * HF + h * FF;
        const float* as = a_src + h * FF;
        const float* ad = a_dst + h * FF;
        float s = 0.f;
        #pragma unroll 8
        for (int f = 0; f < FF; ++f) s += wr[f] * (as[f] + ad[f]);
        bv[t] = s;   // t = b*8+h
    }
}

// ---------------- K3: attention, feature-half split (z), upper-bound shift (no max pass)
__global__ void __launch_bounds__(256) k_attn(
    const float* __restrict__ wh, const float* __restrict__ whv,
    const float* __restrict__ es, const float* __restrict__ ed,
    const unsigned* __restrict__ edmax_key, const float* __restrict__ bv,
    const int* __restrict__ list, const int* __restrict__ cnt,
    const float* __restrict__ pool_q,
    float* __restrict__ xout, float* __restrict__ scores_half)
{
    int i = blockIdx.x, z = blockIdx.y, t = threadIdx.x;
    int lane = t & 63, wid = t >> 6;
    int nn = cnt[i];

    __shared__ float att[KT * 32];     // [k][hl*8+b] 16 KB
    __shared__ int jl[KT];
    __shared__ float base_s[32], M_s[32], inv_s[32];
    __shared__ float red[8][32];
    __shared__ float red2[4][BB];

    if (t < 32) {
        int hl = t >> 3, b = t & 7, h = z * 4 + hl;
        float base = es[i * 8 + h] + bv[b * 8 + h];
        base_s[t] = base;
        float mv = base + fdec(edmax_key[h]);   // >= any neighbor's pre-leaky e
        M_s[t] = mv > 0.f ? mv : 0.2f * mv;     // leaky is monotone -> valid upper bound
    }
    __syncthreads();

    int p = t & 31;
    int hp = z * 4 + (p >> 3);
    float basev = base_s[p], Mv = M_s[p];
    float ssum = 0.f;
    float ac0=0,ac1=0,ac2=0,ac3=0,ac4=0,ac5=0,ac6=0,ac7=0;
    int hl8 = (t >> 6) * 8;
    int fg = z * 256 + t;

    for (int c0 = 0; c0 < nn; c0 += KT) {
        int kc = min(KT, nn - c0);
        __syncthreads();
        if (t < kc) jl[t] = list[i * NN + c0 + t];
        __syncthreads();
        for (int k = t >> 5; k < kc; k += 8) {
            int j = jl[k];
            float e = basev + ed[j * 8 + hp];
            e = e > 0.f ? e : 0.2f * e;
            float pe = __expf(e - Mv);
            ssum += pe;
            att[k * 32 + p] = pe;
        }
        __syncthreads();
        #pragma unroll 2
        for (int k = 0; k < kc; ++k) {
            float r = wh[jl[k] * HF + fg];
            const float4 aA = *(const float4*)&att[k * 32 + hl8];
            const float4 aB = *(const float4*)&att[k * 32 + hl8 + 4];
            ac0 += aA.x * r; ac1 += aA.y * r; ac2 += aA.z * r; ac3 += aA.w * r;
            ac4 += aB.x * r; ac5 += aB.y * r; ac6 += aB.z * r; ac7 += aB.w * r;
        }
    }
    __syncthreads();
    red[t >> 5][p] = ssum;
    __syncthreads();
    if (t < 32) {
        float s = 0.f;
        #pragma unroll
        for (int g = 0; g < 8; ++g) s += red[g][t];
        inv_s[t] = 1.0f / s;
    }
    __syncthreads();

    int hl = t >> 6;
    float pqv = pool_q[fg];
    float accs[8] = {ac0,ac1,ac2,ac3,ac4,ac5,ac6,ac7};
    #pragma unroll
    for (int b = 0; b < BB; ++b) {
        float o = accs[b] * inv_s[hl * 8 + b] + whv[b * HF + fg];
        o = o > 0.f ? o : (__expf(o) - 1.f);
        xout[(b * NN + i) * HF + fg] = o;
        float sp = o * pqv;
        #pragma unroll
        for (int off = 32; off > 0; off >>= 1) sp += __shfl_down(sp, off);
        if (lane == 0) red2[wid][b] = sp;
    }
    __syncthreads();
    if (t < BB)
        scores_half[(z * BB + t) * NN + i] = red2[0][t] + red2[1][t] + red2[2][t] + red2[3][t];
}

// ---------------- K4: per-batch node softmax -> normalized weights
__global__ void __launch_bounds__(256) k_smax(const float* __restrict__ sh2,
                                              float* __restrict__ wn)
{
    int b = blockIdx.x, t = threadIdx.x, lane = t & 63, wid = t >> 6;
    __shared__ float red[4];
    __shared__ float sM, sI;
    float v[4];
    float mx = -1e30f;
    #pragma unroll
    for (int q = 0; q < 4; ++q) {
        int n = q * 256 + t;
        v[q] = sh2[b * NN + n] + sh2[(BB + b) * NN + n];
        mx = fmaxf(mx, v[q]);
    }
    #pragma unroll
    for (int off = 32; off > 0; off >>= 1) mx = fmaxf(mx, __shfl_down(mx, off));
    if (lane == 0) red[wid] = mx;
    __syncthreads();
    if (t == 0) sM = fmaxf(fmaxf(red[0], red[1]), fmaxf(red[2], red[3]));
    __syncthreads();
    float sm = 0.f;
    #pragma unroll
    for (int q = 0; q < 4; ++q) { v[q] = __expf(v[q] - sM); sm += v[q]; }
    #pragma unroll
    for (int off = 32; off > 0; off >>= 1) sm += __shfl_down(sm, off);
    __syncthreads();
    if (lane == 0) red[wid] = sm;
    __syncthreads();
    if (t == 0) sI = 1.0f / (red[0] + red[1] + red[2] + red[3]);
    __syncthreads();
    #pragma unroll
    for (int q = 0; q < 4; ++q) wn[b * NN + q * 256 + t] = v[q] * sI;
}

// ---------------- K5: pooling partials (atomic into zeroed pooled)
__global__ void __launch_bounds__(256) k_pool(const float* __restrict__ xout,
    const float* __restrict__ wn, float* __restrict__ pooled)
{
    int q = blockIdx.x, b = blockIdx.y, t = threadIdx.x;
    __shared__ float wl[64];
    if (t < 64) wl[t] = wn[b * NN + q * 64 + t];
    __syncthreads();
    int f0 = 2 * t;
    float ax = 0.f, ay = 0.f;
    #pragma unroll 4
    for (int n = 0; n < 64; ++n) {
        float w = wl[n];
        const float2 r = *(const float2*)&xout[((b * NN + q * 64 + n)) * HF + f0];
        ax += w * r.x; ay += w * r.y;
    }
    atomicAdd(&pooled[b * HF + f0], ax);
    atomicAdd(&pooled[b * HF + f0 + 1], ay);
}

// ---------------- K6: FC (k-quarters, atomic into zeroed out; bias at q==0)
__global__ void __launch_bounds__(256) k_fc(const float* __restrict__ pooled,
    const float* __restrict__ fc_W, const float* __restrict__ fc_b,
    float* __restrict__ out)
{
    int q = blockIdx.x, b = blockIdx.y, t = threadIdx.x;
    __shared__ float pl[128];
    if (t < 128) pl[t] = pooled[b * HF + q * 128 + t];
    __syncthreads();
    int f0 = 2 * t;
    float ax = 0.f, ay = 0.f;
    if (q == 0) { ax = fc_b[f0]; ay = fc_b[f0 + 1]; }
    #pragma unroll 4
    for (int kk = 0; kk < 128; ++kk) {
        float pv = pl[kk];
        const float2 wv = *(const float2*)&fc_W[(q * 128 + kk) * HF + f0];
        ax += pv * wv.x; ay += pv * wv.y;
    }
    atomicAdd(&out[b * HF + f0], ax);
    atomicAdd(&out[b * HF + f0 + 1], ay);
}

extern "C" void kernel_launch(void* const* d_in, const int* in_sizes, int n_in,
                              void* d_out, int out_size, void* d_ws, size_t ws_size,
                              hipStream_t stream) {
    const float* vis   = (const float*)d_in[0];
    const float* lab   = (const float*)d_in[1];
    const float* adj   = (const float*)d_in[2];
    const float* Wm    = (const float*)d_in[3];
    const float* a_src = (const float*)d_in[4];
    const float* a_dst = (const float*)d_in[5];
    const float* pq    = (const float*)d_in[6];
    const float* fcW   = (const float*)d_in[7];
    const float* fcb   = (const float*)d_in[8];
    float* out = (float*)d_out;

    char* w = (char*)d_ws;
    // ---- zero region (one zero kernel): wh, whv, pooled, edmax ----
    float*    wh     = (float*)w;    w += (size_t)NN * HF * 4;      // 2 MB
    float*    whv    = (float*)w;    w += (size_t)BB * HF * 4;      // 16 KB
    float*    pooled = (float*)w;    w += (size_t)BB * HF * 4;      // 16 KB
    unsigned* edmax  = (unsigned*)w; w += 256;                       // 8 keys + pad
    size_t zbytes = (size_t)NN * HF * 4 + 2 * (size_t)BB * HF * 4 + 256;
    // ---- plain-store region ----
    float* P      = (float*)w;  w += 256 * 16 * 4;                  // 16 KB
    float* bv     = (float*)w;  w += 64 * 4;
    float* es     = (float*)w;  w += (size_t)NN * HH * 4;
    float* ed     = (float*)w;  w += (size_t)NN * HH * 4;
    int*   nlist  = (int*)w;    w += (size_t)NN * NN * 4;           // 4 MB
    int*   ncnt   = (int*)w;    w += (size_t)NN * 4;
    float* xout   = (float*)w;  w += (size_t)BB * NN * HF * 4;      // 16 MB
    float* sch    = (float*)w;  w += (size_t)2 * BB * NN * 4;       // 64 KB
    float* wn     = (float*)w;  w += (size_t)BB * NN * 4;           // 32 KB

    k_zero<<<544, 256, 0, stream>>>((float4*)wh, (int)(zbytes / 16),
                                    (float4*)out, (int)((size_t)BB * HF * 4 / 16));
    k_prep<<<800, 256, 0, stream>>>(lab, vis, adj, Wm, a_src, a_dst,
                                    wh, whv, P, nlist, ncnt);
    k_prep2<<<65, 256, 0, stream>>>(lab, P, whv, a_src, a_dst, es, ed, edmax, bv);
    k_attn<<<dim3(NN, 2), 256, 0, stream>>>(wh, whv, es, ed, edmax, bv,
                                            nlist, ncnt, pq, xout, sch);
    k_smax<<<BB, 256, 0, stream>>>(sch, wn);
    k_pool<<<dim3(16, BB), 256, 0, stream>>>(xout, wn, pooled);
    k_fc<<<dim3(4, BB), 256, 0, stream>>>(pooled, fcW, fcb, out);
}

// Round 6
// 90.439 us; speedup vs baseline: 2.9786x; 1.1457x over previous
//
#include <hip/hip_runtime.h>

#define NN 1024
#define BB 8
#define HH 8
#define FF 64
#define HF 512
#define KT 128

__device__ __forceinline__ unsigned fkey(float x) {
    unsigned u = __float_as_uint(x);
    return (u & 0x80000000u) ? ~u : (u | 0x80000000u);
}
__device__ __forceinline__ float fdec(unsigned k) {
    return (k & 0x80000000u) ? __uint_as_float(k ^ 0x80000000u) : __uint_as_float(~k);
}

// ---------------- K1: fused prep
//  bx 0..1023   : wh_lab GEMM, 4 nodes x K-quarter -> whP[kq] (plain stores)
//  bx 1024..1039: P projection
//  bx 1040..1055: whv partials -> whv2[kh]
//  bx 1056..1311: adjacency compaction (4 rows/block)
//  bx 1312      : zero pooled/out/edmax
__global__ void __launch_bounds__(256) k_prep(
    const float* __restrict__ lab, const float* __restrict__ vis,
    const float* __restrict__ adj, const float* __restrict__ Wm,
    const float* __restrict__ a_src, const float* __restrict__ a_dst,
    float* __restrict__ whP, float* __restrict__ whv2, float* __restrict__ P,
    int* __restrict__ list, int* __restrict__ cnt,
    float* __restrict__ pooled, float* __restrict__ outp,
    unsigned* __restrict__ edmax)
{
    int bx = blockIdx.x, t = threadIdx.x;
    __shared__ float sh[512];
    if (bx < 1024) {
        int np = bx >> 2, kq = bx & 3, n0 = np * 4;
        sh[t] = lab[(n0 + (t >> 6)) * 256 + kq * 64 + (t & 63)];
        __syncthreads();
        float a00=0,a01=0,a10=0,a11=0,a20=0,a21=0,a30=0,a31=0;
        const float* wp = Wm + (size_t)(kq * 64) * HF;
        #pragma unroll 8
        for (int i = 0; i < 64; ++i) {
            float w0 = wp[i * HF + t], w1 = wp[i * HF + t + 256];
            float x0 = sh[i], x1 = sh[64 + i], x2 = sh[128 + i], x3 = sh[192 + i];
            a00 += x0*w0; a01 += x0*w1; a10 += x1*w0; a11 += x1*w1;
            a20 += x2*w0; a21 += x2*w1; a30 += x3*w0; a31 += x3*w1;
        }
        float* dst = whP + (size_t)kq * NN * HF;
        dst[(n0+0)*HF + t] = a00; dst[(n0+0)*HF + t + 256] = a01;
        dst[(n0+1)*HF + t] = a10; dst[(n0+1)*HF + t + 256] = a11;
        dst[(n0+2)*HF + t] = a20; dst[(n0+2)*HF + t + 256] = a21;
        dst[(n0+3)*HF + t] = a30; dst[(n0+3)*HF + t + 256] = a31;
    } else if (bx < 1040) {
        int ib = bx - 1024;
        int i = ib * 16 + (t >> 4), c = t & 15, h = c >> 1;
        const float* av = ((c & 1) ? a_dst : a_src) + h * FF;
        const float* wr = Wm + (size_t)i * HF + h * FF;
        float s = 0.f;
        #pragma unroll
        for (int f = 0; f < FF; ++f) s += wr[f] * av[f];
        P[i * 16 + c] = s;
    } else if (bx < 1056) {
        int id = bx - 1040, kh = id & 1, b = id >> 1;
        sh[t] = vis[b * 512 + kh * 256 + t];
        __syncthreads();
        float a0 = 0.f, a1 = 0.f;
        const float* wp = Wm + (size_t)(256 + kh * 256) * HF;
        #pragma unroll 4
        for (int i = 0; i < 256; ++i) {
            float xv = sh[i];
            a0 += xv * wp[i * HF + t];
            a1 += xv * wp[i * HF + t + 256];
        }
        whv2[(kh * BB + b) * HF + t] = a0;
        whv2[(kh * BB + b) * HF + t + 256] = a1;
    } else if (bx < 1312) {
        int id = bx - 1056;
        int i = id * 4 + (t >> 6), lane = t & 63;
        int base = 0;
        for (int c = 0; c < 16; ++c) {
            int j = c * 64 + lane;
            bool pres = adj[(size_t)i * NN + j] > 0.f;
            unsigned long long m = __ballot(pres);
            int pos = __popcll(m & ((1ull << lane) - 1ull));
            if (pres) list[i * NN + base + pos] = j;
            base += __popcll(m);
        }
        if (lane == 0) cnt[i] = base;
    } else {
        float4 z; z.x = 0.f; z.y = 0.f; z.z = 0.f; z.w = 0.f;
        float4* pp = (float4*)pooled;
        float4* oo = (float4*)outp;
        #pragma unroll
        for (int q = 0; q < 4; ++q) { pp[q * 256 + t] = z; oo[q * 256 + t] = z; }
        if (t < 8) edmax[t] = 0u;
    }
}

// ---------------- K2: es/ed (+edmax), wh = sum of 4 quarters, whv sum + bv
//  bx 0..63: es/ed ; bx 64..95: wh sum ; bx 96: whv sum + bv
__global__ void __launch_bounds__(256) k_prep2(
    const float* __restrict__ lab, const float* __restrict__ P,
    const float* __restrict__ whv2,
    const float* __restrict__ a_src, const float* __restrict__ a_dst,
    const float* __restrict__ whP, float* __restrict__ wh, float* __restrict__ whv,
    float* __restrict__ es, float* __restrict__ ed,
    unsigned* __restrict__ edmax_key, float* __restrict__ bv)
{
    int bx = blockIdx.x, t = threadIdx.x;
    if (bx < 64) {
        __shared__ float labS[16 * 256];
        __shared__ float edsh[16][8];
        int n0 = bx * 16;
        for (int u = t; u < 4096; u += 256)
            labS[u] = lab[(n0 + (u >> 8)) * 256 + (u & 255)];
        __syncthreads();
        int nd = t >> 4, c = t & 15, h = c >> 1, sd = c & 1;
        const float* xr = labS + nd * 256;
        float s = 0.f;
        #pragma unroll 8
        for (int i = 0; i < 256; ++i) s += xr[i] * P[i * 16 + c];
        int n = n0 + nd;
        if (sd) { ed[n * 8 + h] = s; edsh[nd][h] = s; }
        else es[n * 8 + h] = s;
        __syncthreads();
        if (t < 8) {
            float m = -1e30f;
            #pragma unroll
            for (int q = 0; q < 16; ++q) m = fmaxf(m, edsh[q][t]);
            atomicMax(&edmax_key[t], fkey(m));
        }
    } else if (bx < 96) {
        int blk = bx - 64;
        const size_t Q = (size_t)NN * HF / 4;   // float4 per quarter buffer
        const float4* A = (const float4*)whP;
        const float4* B4 = A + Q;
        const float4* C4 = B4 + Q;
        const float4* D4 = C4 + Q;
        float4* W4 = (float4*)wh;
        int base = blk * 4096;
        #pragma unroll
        for (int q = 0; q < 16; ++q) {
            int idx = base + q * 256 + t;
            float4 a = A[idx], b = B4[idx], c = C4[idx], d = D4[idx];
            float4 r;
            r.x = a.x + b.x + c.x + d.x; r.y = a.y + b.y + c.y + d.y;
            r.z = a.z + b.z + c.z + d.z; r.w = a.w + b.w + c.w + d.w;
            W4[idx] = r;
        }
    } else {
        const float4* p0 = (const float4*)whv2;
        const float4* p1 = (const float4*)(whv2 + BB * HF);
        float4* w4 = (float4*)whv;
        #pragma unroll
        for (int q = 0; q < 4; ++q) {
            int idx = q * 256 + t;
            float4 a = p0[idx], b = p1[idx];
            float4 r;
            r.x = a.x + b.x; r.y = a.y + b.y; r.z = a.z + b.z; r.w = a.w + b.w;
            w4[idx] = r;
        }
        if (t < 64) {
            int b = t >> 3, h = t & 7;
            const float* w0 = whv2 + b * HF + h * FF;
            const float* w1 = whv2 + BB * HF + b * HF + h * FF;
            const float* as = a_src + h * FF;
            const float* ad = a_dst + h * FF;
            float s = 0.f;
            #pragma unroll 8
            for (int f = 0; f < FF; ++f) s += (w0[f] + w1[f]) * (as[f] + ad[f]);
            bv[t] = s;
        }
    }
}

// ---------------- K3: attention (feature-half split z; 2-k-parallel float2 C-loop)
__global__ void __launch_bounds__(256) k_attn(
    const float* __restrict__ wh, const float* __restrict__ whv,
    const float* __restrict__ es, const float* __restrict__ ed,
    const unsigned* __restrict__ edmax_key, const float* __restrict__ bv,
    const int* __restrict__ list, const int* __restrict__ cnt,
    const float* __restrict__ pool_q,
    float* __restrict__ xout, float* __restrict__ scores_half)
{
    int i = blockIdx.x, z = blockIdx.y, t = threadIdx.x;
    int nn = cnt[i];

    __shared__ float att[(KT + 2) * 32];   // [k][hl*8+b]; reused as merge buffer
    __shared__ int jl[KT + 2];
    __shared__ float base_s[32], M_s[32], inv_s[32];
    __shared__ float red[8][32];
    __shared__ float red2[4][BB];

    if (t < 32) {
        int hl = t >> 3, b = t & 7, h = z * 4 + hl;
        float base = es[i * 8 + h] + bv[b * 8 + h];
        base_s[t] = base;
        float mv = base + fdec(edmax_key[h]);   // >= any neighbor's pre-leaky e
        M_s[t] = mv > 0.f ? mv : 0.2f * mv;     // leaky monotone -> valid upper bound
    }
    __syncthreads();

    int p = t & 31;
    int hp = z * 4 + (p >> 3);
    float basev = base_s[p], Mv = M_s[p];
    float ssum = 0.f;

    int kp = t >> 7;          // 0/1: which parity of k this thread aggregates
    int tf = t & 127;         // feature-pair lane
    int f0 = z * 256 + 2 * tf;
    int hl8 = (tf >> 5) * 8;
    float ac[16];
    #pragma unroll
    for (int q = 0; q < 16; ++q) ac[q] = 0.f;

    for (int c0 = 0; c0 < nn; c0 += KT) {
        int kc = min(KT, nn - c0);
        int kc2 = (kc + 1) & ~1;
        __syncthreads();
        if (t < kc) jl[t] = list[i * NN + c0 + t];
        else if (t < kc2) jl[t] = 0;
        __syncthreads();
        for (int k = t >> 5; k < kc; k += 8) {
            int j = jl[k];
            float e = basev + ed[j * 8 + hp];
            e = e > 0.f ? e : 0.2f * e;
            float pe = __expf(e - Mv);
            ssum += pe;
            att[k * 32 + p] = pe;
        }
        if ((kc & 1) && t < 32) att[kc * 32 + t] = 0.f;
        __syncthreads();
        #pragma unroll 2
        for (int k = 0; k < kc2; k += 2) {
            int kk = k + kp;
            const float2 r = *(const float2*)&wh[(size_t)jl[kk] * HF + f0];
            const float4 aA = *(const float4*)&att[kk * 32 + hl8];
            const float4 aB = *(const float4*)&att[kk * 32 + hl8 + 4];
            ac[0]  += aA.x * r.x; ac[1]  += aA.x * r.y;
            ac[2]  += aA.y * r.x; ac[3]  += aA.y * r.y;
            ac[4]  += aA.z * r.x; ac[5]  += aA.z * r.y;
            ac[6]  += aA.w * r.x; ac[7]  += aA.w * r.y;
            ac[8]  += aB.x * r.x; ac[9]  += aB.x * r.y;
            ac[10] += aB.y * r.x; ac[11] += aB.y * r.y;
            ac[12] += aB.z * r.x; ac[13] += aB.z * r.y;
            ac[14] += aB.w * r.x; ac[15] += aB.w * r.y;
        }
    }
    __syncthreads();                       // all att reads done
    red[t >> 5][p] = ssum;
    float* mrg = (float*)att;              // reuse att space for kp-merge
    if (kp == 1) {
        #pragma unroll
        for (int q = 0; q < 16; ++q) mrg[tf * 16 + q] = ac[q];
    }
    __syncthreads();
    if (t < 32) {
        float s = 0.f;
        #pragma unroll
        for (int g = 0; g < 8; ++g) s += red[g][t];
        inv_s[t] = 1.0f / s;
    }
    __syncthreads();
    if (kp == 0) {
        #pragma unroll
        for (int q = 0; q < 16; ++q) ac[q] += mrg[tf * 16 + q];
    }

    int hl = tf >> 5;
    const float2 pq2 = *(const float2*)&pool_q[f0];
    #pragma unroll
    for (int b = 0; b < BB; ++b) {
        float spv = 0.f;
        if (kp == 0) {
            float iv = inv_s[hl * 8 + b];
            const float2 wv = *(const float2*)&whv[b * HF + f0];
            float o0 = ac[2 * b]     * iv + wv.x;
            float o1 = ac[2 * b + 1] * iv + wv.y;
            o0 = o0 > 0.f ? o0 : (__expf(o0) - 1.f);
            o1 = o1 > 0.f ? o1 : (__expf(o1) - 1.f);
            float2 ov; ov.x = o0; ov.y = o1;
            *(float2*)&xout[((size_t)b * NN + i) * HF + f0] = ov;
            spv = o0 * pq2.x + o1 * pq2.y;
        }
        #pragma unroll
        for (int off = 32; off > 0; off >>= 1) spv += __shfl_down(spv, off);
        if ((t & 63) == 0) red2[t >> 6][b] = spv;
    }
    __syncthreads();
    if (t < BB)
        scores_half[(z * BB + t) * NN + i] = red2[0][t] + red2[1][t] + red2[2][t] + red2[3][t];
}

// ---------------- K4: fused node softmax (redundant per block) + pooling partials
__global__ void __launch_bounds__(256) k_smax_pool(const float* __restrict__ sch,
    const float* __restrict__ xout, float* __restrict__ pooled)
{
    int q = blockIdx.x, b = blockIdx.y, t = threadIdx.x;
    int lane = t & 63, wid = t >> 6;
    __shared__ float red[4];
    __shared__ float sM, sI;
    __shared__ float wl[64];

    float v[4];
    float mx = -1e30f;
    #pragma unroll
    for (int qq = 0; qq < 4; ++qq) {
        int n = qq * 256 + t;
        v[qq] = sch[b * NN + n] + sch[(BB + b) * NN + n];
        mx = fmaxf(mx, v[qq]);
    }
    #pragma unroll
    for (int off = 32; off > 0; off >>= 1) mx = fmaxf(mx, __shfl_down(mx, off));
    if (lane == 0) red[wid] = mx;
    __syncthreads();
    if (t == 0) sM = fmaxf(fmaxf(red[0], red[1]), fmaxf(red[2], red[3]));
    __syncthreads();
    float sm = 0.f;
    #pragma unroll
    for (int qq = 0; qq < 4; ++qq) sm += __expf(v[qq] - sM);
    #pragma unroll
    for (int off = 32; off > 0; off >>= 1) sm += __shfl_down(sm, off);
    __syncthreads();
    if (lane == 0) red[wid] = sm;
    __syncthreads();
    if (t == 0) sI = 1.0f / (red[0] + red[1] + red[2] + red[3]);
    __syncthreads();

    if (t < 64) {
        int n = q * 64 + t;
        float s = sch[b * NN + n] + sch[(BB + b) * NN + n];
        wl[t] = __expf(s - sM) * sI;
    }
    __syncthreads();

    int f0 = 2 * t;
    float ax = 0.f, ay = 0.f;
    #pragma unroll 4
    for (int n = 0; n < 64; ++n) {
        float w = wl[n];
        const float2 r = *(const float2*)&xout[((size_t)b * NN + q * 64 + n) * HF + f0];
        ax += w * r.x; ay += w * r.y;
    }
    atomicAdd(&pooled[b * HF + f0], ax);
    atomicAdd(&pooled[b * HF + f0 + 1], ay);
}

// ---------------- K5: FC (K-eighths, atomic into zeroed out; bias at q==0)
__global__ void __launch_bounds__(256) k_fc(const float* __restrict__ pooled,
    const float* __restrict__ fc_W, const float* __restrict__ fc_b,
    float* __restrict__ out)
{
    int q = blockIdx.x, b = blockIdx.y, t = threadIdx.x;
    __shared__ float pl[64];
    if (t < 64) pl[t] = pooled[b * HF + q * 64 + t];
    __syncthreads();
    int f0 = 2 * t;
    float ax = 0.f, ay = 0.f;
    if (q == 0) { ax = fc_b[f0]; ay = fc_b[f0 + 1]; }
    #pragma unroll 4
    for (int kk = 0; kk < 64; ++kk) {
        float pv = pl[kk];
        const float2 wv = *(const float2*)&fc_W[(size_t)(q * 64 + kk) * HF + f0];
        ax += pv * wv.x; ay += pv * wv.y;
    }
    atomicAdd(&out[b * HF + f0], ax);
    atomicAdd(&out[b * HF + f0 + 1], ay);
}

extern "C" void kernel_launch(void* const* d_in, const int* in_sizes, int n_in,
                              void* d_out, int out_size, void* d_ws, size_t ws_size,
                              hipStream_t stream) {
    const float* vis   = (const float*)d_in[0];
    const float* lab   = (const float*)d_in[1];
    const float* adj   = (const float*)d_in[2];
    const float* Wm    = (const float*)d_in[3];
    const float* a_src = (const float*)d_in[4];
    const float* a_dst = (const float*)d_in[5];
    const float* pq    = (const float*)d_in[6];
    const float* fcW   = (const float*)d_in[7];
    const float* fcb   = (const float*)d_in[8];
    float* out = (float*)d_out;

    char* w = (char*)d_ws;
    float*    whP    = (float*)w;    w += (size_t)4 * NN * HF * 4;  // 8 MB
    float*    wh     = (float*)w;    w += (size_t)NN * HF * 4;      // 2 MB
    float*    whv2   = (float*)w;    w += (size_t)2 * BB * HF * 4;  // 32 KB
    float*    whv    = (float*)w;    w += (size_t)BB * HF * 4;      // 16 KB
    float*    pooled = (float*)w;    w += (size_t)BB * HF * 4;      // 16 KB
    unsigned* edmax  = (unsigned*)w; w += 256;
    float*    P      = (float*)w;    w += 256 * 16 * 4;             // 16 KB
    float*    bv     = (float*)w;    w += 64 * 4;
    float*    es     = (float*)w;    w += (size_t)NN * HH * 4;
    float*    ed     = (float*)w;    w += (size_t)NN * HH * 4;
    int*      nlist  = (int*)w;      w += (size_t)NN * NN * 4;      // 4 MB
    int*      ncnt   = (int*)w;      w += (size_t)NN * 4;
    float*    xout   = (float*)w;    w += (size_t)BB * NN * HF * 4; // 16 MB
    float*    sch    = (float*)w;    w += (size_t)2 * BB * NN * 4;  // 64 KB

    k_prep<<<1313, 256, 0, stream>>>(lab, vis, adj, Wm, a_src, a_dst,
                                     whP, whv2, P, nlist, ncnt, pooled, out, edmax);
    k_prep2<<<97, 256, 0, stream>>>(lab, P, whv2, a_src, a_dst, whP, wh, whv,
                                    es, ed, edmax, bv);
    k_attn<<<dim3(NN, 2), 256, 0, stream>>>(wh, whv, es, ed, edmax, bv,
                                            nlist, ncnt, pq, xout, sch);
    k_smax_pool<<<dim3(16, BB), 256, 0, stream>>>(sch, xout, pooled);
    k_fc<<<dim3(8, BB), 256, 0, stream>>>(pooled, fcW, fcb, out);
}